// Round 1
// baseline (459.524 us; speedup 1.0000x reference)
//
#include <hip/hip_runtime.h>

// CAM module: energy = q qT (bf16x3 split for fp32 accuracy), softmin, out = attn q, gamma*out + x
// B=16, C=512, N=64*64=4096

#define BATCH 16
#define CCH   512
#define NSP   4096

typedef __attribute__((ext_vector_type(8))) short bfx8;
typedef __attribute__((ext_vector_type(4))) short bfx4;
typedef __attribute__((ext_vector_type(4))) float fx4;

__device__ __forceinline__ short f2bf(float v) {
    union { float f; unsigned u; } a; a.f = v;
    unsigned r = a.u + 0x7fffu + ((a.u >> 16) & 1u);   // RNE
    return (short)(r >> 16);
}
__device__ __forceinline__ float bf2f(short s) {
    union { unsigned u; float f; } a; a.u = ((unsigned)(unsigned short)s) << 16;
    return a.f;
}

// ---------------- Kernel 1: energy[b,c,d] = sum_n q[b,c,n] q[b,d,n]  (bf16x3) ----------------
// 64x64 tile per block, 4 waves (each 32x32), BK=32, K=4096.
__global__ __launch_bounds__(256) void energy_kernel(const float* __restrict__ x,
                                                     float* __restrict__ energy) {
    int blk = blockIdx.x;
    int b   = blk >> 6;         // 64 tiles per batch (8x8)
    int t   = blk & 63;
    int c0  = (t >> 3) * 64;
    int d0  = (t & 7) * 64;
    const float* qb = x + (size_t)b * CCH * NSP;

    __shared__ short Ah[64][32];
    __shared__ short Al[64][32];
    __shared__ short Bh[64][32];
    __shared__ short Bl[64][32];

    int tid  = threadIdx.x;
    int lane = tid & 63;
    int w    = tid >> 6;
    int wr   = (w >> 1) * 32;
    int wc   = (w & 1) * 32;

    fx4 acc[2][2];
#pragma unroll
    for (int i = 0; i < 2; i++)
#pragma unroll
        for (int j = 0; j < 2; j++) acc[i][j] = (fx4)(0.0f);

    for (int kt = 0; kt < NSP / 32; ++kt) {
        __syncthreads();   // protect LDS from previous iteration's readers
#pragma unroll
        for (int s = 0; s < 2; ++s) {
            int idx = s * 256 + tid;       // 0..511
            int r   = idx >> 3;            // row 0..63
            int f4  = idx & 7;             // float4 slot in row
            const float* pa = qb + (size_t)(c0 + r) * NSP + kt * 32 + f4 * 4;
            const float* pb = qb + (size_t)(d0 + r) * NSP + kt * 32 + f4 * 4;
            fx4 av = *(const fx4*)pa;
            fx4 bv = *(const fx4*)pb;
            bfx4 ah, al, bh, bl;
#pragma unroll
            for (int e = 0; e < 4; ++e) {
                float v = av[e];
                short h = f2bf(v);
                ah[e] = h;
                al[e] = f2bf(v - bf2f(h));
                v = bv[e];
                h = f2bf(v);
                bh[e] = h;
                bl[e] = f2bf(v - bf2f(h));
            }
            *(bfx4*)&Ah[r][f4 * 4] = ah;
            *(bfx4*)&Al[r][f4 * 4] = al;
            *(bfx4*)&Bh[r][f4 * 4] = bh;
            *(bfx4*)&Bl[r][f4 * 4] = bl;
        }
        __syncthreads();

        int rowk = (lane >> 4) * 8;        // k offset within BK
        bfx8 afh[2], afl[2], bfh[2], bfl[2];
#pragma unroll
        for (int mi = 0; mi < 2; ++mi) {
            int r = wr + mi * 16 + (lane & 15);
            afh[mi] = *(const bfx8*)&Ah[r][rowk];
            afl[mi] = *(const bfx8*)&Al[r][rowk];
        }
#pragma unroll
        for (int ni = 0; ni < 2; ++ni) {
            int r = wc + ni * 16 + (lane & 15);
            bfh[ni] = *(const bfx8*)&Bh[r][rowk];
            bfl[ni] = *(const bfx8*)&Bl[r][rowk];
        }
#pragma unroll
        for (int mi = 0; mi < 2; ++mi)
#pragma unroll
            for (int ni = 0; ni < 2; ++ni) {
                acc[mi][ni] = __builtin_amdgcn_mfma_f32_16x16x32_bf16(afh[mi], bfh[ni], acc[mi][ni], 0, 0, 0);
                acc[mi][ni] = __builtin_amdgcn_mfma_f32_16x16x32_bf16(afh[mi], bfl[ni], acc[mi][ni], 0, 0, 0);
                acc[mi][ni] = __builtin_amdgcn_mfma_f32_16x16x32_bf16(afl[mi], bfh[ni], acc[mi][ni], 0, 0, 0);
            }
    }

    // C/D layout (m89-verified): col = lane&15, row = (lane>>4)*4 + reg
    int colw = lane & 15;
    int rowg = (lane >> 4) * 4;
#pragma unroll
    for (int mi = 0; mi < 2; ++mi)
#pragma unroll
        for (int ni = 0; ni < 2; ++ni) {
            int c = c0 + wr + mi * 16 + rowg;
            int d = d0 + wc + ni * 16 + colw;
#pragma unroll
            for (int r = 0; r < 4; ++r)
                energy[((size_t)b * CCH + (c + r)) * CCH + d] = acc[mi][ni][r];
        }
}

// ---------------- Kernel 2: in-place softmin over rows of energy ----------------
// attention[c,d] = exp(min_d(e) - e[c,d]) / sum
__global__ __launch_bounds__(256) void softmax_kernel(float* __restrict__ energy) {
    size_t row = blockIdx.x;                  // 0..B*C-1
    float* e = energy + row * CCH;
    int tid = threadIdx.x;
    float v0 = e[tid];
    float v1 = e[tid + 256];

    float m = fminf(v0, v1);
#pragma unroll
    for (int off = 32; off; off >>= 1) m = fminf(m, __shfl_xor(m, off));
    __shared__ float redm[4];
    __shared__ float reds[4];
    if ((tid & 63) == 0) redm[tid >> 6] = m;
    __syncthreads();
    m = fminf(fminf(redm[0], redm[1]), fminf(redm[2], redm[3]));

    float w0 = __expf(m - v0);
    float w1 = __expf(m - v1);
    float s = w0 + w1;
#pragma unroll
    for (int off = 32; off; off >>= 1) s += __shfl_xor(s, off);
    if ((tid & 63) == 0) reds[tid >> 6] = s;
    __syncthreads();
    s = (reds[0] + reds[1]) + (reds[2] + reds[3]);
    float inv = 1.0f / s;
    e[tid]       = w0 * inv;
    e[tid + 256] = w1 * inv;
}

// ---------------- Kernel 3: out = gamma * (attn @ q) + x ----------------
// BM=64 (c) x BN=128 (n), BK=32 (d). A=attn row-major (easy K-contig frags),
// B=q staged transposed into LDS [n][d] with 2-bit XOR swizzle on the 16B block.
__global__ __launch_bounds__(256) void out_kernel(const float* __restrict__ x,
                                                  const float* __restrict__ attn,
                                                  const float* __restrict__ gamma,
                                                  float* __restrict__ out) {
    int blk = blockIdx.x;
    int b   = blk >> 8;                 // 256 tiles per batch (8 x 32)
    int t   = blk & 255;
    int c0  = (t >> 5) * 64;
    int n0  = (t & 31) * 128;
    const float* qb = x + (size_t)b * CCH * NSP;
    const float* ab = attn + (size_t)b * CCH * CCH;

    __shared__ short As[64][32];
    __shared__ short Bt[128][32];       // [n][d], rows 64B, XOR-swizzled 16B blocks
    char* btbase = (char*)&Bt[0][0];

    int tid  = threadIdx.x;
    int lane = tid & 63;
    int w    = tid >> 6;
    int wr   = (w >> 1) * 32;           // c offset of wave
    int wc   = (w & 1) * 64;            // n offset of wave

    fx4 acc[2][4];
#pragma unroll
    for (int i = 0; i < 2; i++)
#pragma unroll
        for (int j = 0; j < 4; j++) acc[i][j] = (fx4)(0.0f);

    for (int kt = 0; kt < CCH / 32; ++kt) {
        __syncthreads();
        // A: 64x32 fp32 -> bf16
#pragma unroll
        for (int s = 0; s < 2; ++s) {
            int idx = s * 256 + tid;
            int r   = idx >> 3;
            int f4  = idx & 7;
            fx4 v = *(const fx4*)(ab + (size_t)(c0 + r) * CCH + kt * 32 + f4 * 4);
            bfx4 hv;
#pragma unroll
            for (int e = 0; e < 4; ++e) hv[e] = f2bf(v[e]);
            *(bfx4*)&As[r][f4 * 4] = hv;
        }
        // B: 32(d) x 128(n) fp32, write transposed+swizzled
#pragma unroll
        for (int s = 0; s < 4; ++s) {
            int idx = s * 256 + tid;
            int rd  = idx >> 5;          // d row 0..31
            int c4  = idx & 31;          // float4 col
            fx4 v = *(const fx4*)(qb + (size_t)(kt * 32 + rd) * NSP + n0 + c4 * 4);
#pragma unroll
            for (int j = 0; j < 4; ++j) {
                int n = c4 * 4 + j;
                int byte_in_row = (rd * 2) ^ (((n >> 1) & 3) << 4);
                *(short*)(btbase + n * 64 + byte_in_row) = f2bf(v[j]);
            }
        }
        __syncthreads();

        bfx8 af[2];
#pragma unroll
        for (int mi = 0; mi < 2; ++mi)
            af[mi] = *(const bfx8*)&As[wr + mi * 16 + (lane & 15)][(lane >> 4) * 8];
        bfx8 bf[4];
#pragma unroll
        for (int ni = 0; ni < 4; ++ni) {
            int n = wc + ni * 16 + (lane & 15);
            int byte_in_row = (16 * (lane >> 4)) ^ (((n >> 1) & 3) << 4);
            bf[ni] = *(const bfx8*)(btbase + n * 64 + byte_in_row);
        }
#pragma unroll
        for (int mi = 0; mi < 2; ++mi)
#pragma unroll
            for (int ni = 0; ni < 4; ++ni)
                acc[mi][ni] = __builtin_amdgcn_mfma_f32_16x16x32_bf16(af[mi], bf[ni], acc[mi][ni], 0, 0, 0);
    }

    float g = gamma[0];
    int colw = lane & 15;
    int rowg = (lane >> 4) * 4;
#pragma unroll
    for (int mi = 0; mi < 2; ++mi)
#pragma unroll
        for (int ni = 0; ni < 4; ++ni) {
            int n = n0 + wc + ni * 16 + colw;
#pragma unroll
            for (int r = 0; r < 4; ++r) {
                int c = c0 + wr + mi * 16 + rowg + r;
                size_t off = ((size_t)b * CCH + c) * NSP + n;
                out[off] = g * acc[mi][ni][r] + qb[(size_t)c * NSP + n];
            }
        }
}

extern "C" void kernel_launch(void* const* d_in, const int* in_sizes, int n_in,
                              void* d_out, int out_size, void* d_ws, size_t ws_size,
                              hipStream_t stream) {
    (void)in_sizes; (void)n_in; (void)out_size; (void)ws_size;
    const float* x     = (const float*)d_in[0];
    const float* gamma = (const float*)d_in[1];
    float*       out   = (float*)d_out;
    float*       energy = (float*)d_ws;   // B*C*C fp32 = 16 MiB

    energy_kernel <<<BATCH * 64, 256, 0, stream>>>(x, energy);
    softmax_kernel<<<BATCH * CCH, 256, 0, stream>>>(energy);
    out_kernel    <<<BATCH * 256, 256, 0, stream>>>(x, energy, gamma, out);
}

// Round 2
// 304.531 us; speedup vs baseline: 1.5090x; 1.5090x over previous
//
#include <hip/hip_runtime.h>

// CAM module: energy = q qT (bf16x3 split for fp32 accuracy), softmin, out = attn q, gamma*out + x
// B=16, C=512, N=64*64=4096

#define BATCH 16
#define CCH   512
#define NSP   4096

typedef __attribute__((ext_vector_type(8))) short bfx8;
typedef __attribute__((ext_vector_type(4))) short bfx4;
typedef __attribute__((ext_vector_type(4))) float fx4;

__device__ __forceinline__ short f2bf(float v) {
    union { float f; unsigned u; } a; a.f = v;
    unsigned r = a.u + 0x7fffu + ((a.u >> 16) & 1u);   // RNE
    return (short)(r >> 16);
}
__device__ __forceinline__ float bf2f(short s) {
    union { unsigned u; float f; } a; a.u = ((unsigned)(unsigned short)s) << 16;
    return a.f;
}
__device__ __forceinline__ short f2bf_trunc(float v) {
    return (short)(__float_as_uint(v) >> 16);          // round-toward-zero, 1 VALU op
}

// ---------------- Kernel 1: energy[b,c,d] = sum_n q[b,c,n] q[b,d,n]  (bf16x3) ----------------
// 64x64 tile per block, 4 waves (each 32x32), BK=32, K=4096.
__global__ __launch_bounds__(256) void energy_kernel(const float* __restrict__ x,
                                                     float* __restrict__ energy) {
    int blk = blockIdx.x;
    int b   = blk >> 6;         // 64 tiles per batch (8x8)
    int t   = blk & 63;
    int c0  = (t >> 3) * 64;
    int d0  = (t & 7) * 64;
    const float* qb = x + (size_t)b * CCH * NSP;

    __shared__ short Ah[64][32];
    __shared__ short Al[64][32];
    __shared__ short Bh[64][32];
    __shared__ short Bl[64][32];

    int tid  = threadIdx.x;
    int lane = tid & 63;
    int w    = tid >> 6;
    int wr   = (w >> 1) * 32;
    int wc   = (w & 1) * 32;

    fx4 acc[2][2];
#pragma unroll
    for (int i = 0; i < 2; i++)
#pragma unroll
        for (int j = 0; j < 2; j++) acc[i][j] = (fx4)(0.0f);

    for (int kt = 0; kt < NSP / 32; ++kt) {
        __syncthreads();   // protect LDS from previous iteration's readers
#pragma unroll
        for (int s = 0; s < 2; ++s) {
            int idx = s * 256 + tid;       // 0..511
            int r   = idx >> 3;            // row 0..63
            int f4  = idx & 7;             // float4 slot in row
            const float* pa = qb + (size_t)(c0 + r) * NSP + kt * 32 + f4 * 4;
            const float* pb = qb + (size_t)(d0 + r) * NSP + kt * 32 + f4 * 4;
            fx4 av = *(const fx4*)pa;
            fx4 bv = *(const fx4*)pb;
            bfx4 ah, al, bh, bl;
#pragma unroll
            for (int e = 0; e < 4; ++e) {
                float v = av[e];
                short h = f2bf(v);
                ah[e] = h;
                al[e] = f2bf(v - bf2f(h));
                v = bv[e];
                h = f2bf(v);
                bh[e] = h;
                bl[e] = f2bf(v - bf2f(h));
            }
            *(bfx4*)&Ah[r][f4 * 4] = ah;
            *(bfx4*)&Al[r][f4 * 4] = al;
            *(bfx4*)&Bh[r][f4 * 4] = bh;
            *(bfx4*)&Bl[r][f4 * 4] = bl;
        }
        __syncthreads();

        int rowk = (lane >> 4) * 8;        // k offset within BK
        bfx8 afh[2], afl[2], bfh[2], bfl[2];
#pragma unroll
        for (int mi = 0; mi < 2; ++mi) {
            int r = wr + mi * 16 + (lane & 15);
            afh[mi] = *(const bfx8*)&Ah[r][rowk];
            afl[mi] = *(const bfx8*)&Al[r][rowk];
        }
#pragma unroll
        for (int ni = 0; ni < 2; ++ni) {
            int r = wc + ni * 16 + (lane & 15);
            bfh[ni] = *(const bfx8*)&Bh[r][rowk];
            bfl[ni] = *(const bfx8*)&Bl[r][rowk];
        }
#pragma unroll
        for (int mi = 0; mi < 2; ++mi)
#pragma unroll
            for (int ni = 0; ni < 2; ++ni) {
                acc[mi][ni] = __builtin_amdgcn_mfma_f32_16x16x32_bf16(afh[mi], bfh[ni], acc[mi][ni], 0, 0, 0);
                acc[mi][ni] = __builtin_amdgcn_mfma_f32_16x16x32_bf16(afh[mi], bfl[ni], acc[mi][ni], 0, 0, 0);
                acc[mi][ni] = __builtin_amdgcn_mfma_f32_16x16x32_bf16(afl[mi], bfh[ni], acc[mi][ni], 0, 0, 0);
            }
    }

    // C/D layout (m89-verified): col = lane&15, row = (lane>>4)*4 + reg
    int colw = lane & 15;
    int rowg = (lane >> 4) * 4;
#pragma unroll
    for (int mi = 0; mi < 2; ++mi)
#pragma unroll
        for (int ni = 0; ni < 2; ++ni) {
            int c = c0 + wr + mi * 16 + rowg;
            int d = d0 + wc + ni * 16 + colw;
#pragma unroll
            for (int r = 0; r < 4; ++r)
                energy[((size_t)b * CCH + (c + r)) * CCH + d] = acc[mi][ni][r];
        }
}

// ---------------- Kernel 2: in-place softmin over rows of energy ----------------
// attention[c,d] = exp(min_d(e) - e[c,d]) / sum
__global__ __launch_bounds__(256) void softmax_kernel(float* __restrict__ energy) {
    size_t row = blockIdx.x;                  // 0..B*C-1
    float* e = energy + row * CCH;
    int tid = threadIdx.x;
    float v0 = e[tid];
    float v1 = e[tid + 256];

    float m = fminf(v0, v1);
#pragma unroll
    for (int off = 32; off; off >>= 1) m = fminf(m, __shfl_xor(m, off));
    __shared__ float redm[4];
    __shared__ float reds[4];
    if ((tid & 63) == 0) redm[tid >> 6] = m;
    __syncthreads();
    m = fminf(fminf(redm[0], redm[1]), fminf(redm[2], redm[3]));

    float w0 = __expf(m - v0);
    float w1 = __expf(m - v1);
    float s = w0 + w1;
#pragma unroll
    for (int off = 32; off; off >>= 1) s += __shfl_xor(s, off);
    if ((tid & 63) == 0) reds[tid >> 6] = s;
    __syncthreads();
    s = (reds[0] + reds[1]) + (reds[2] + reds[3]);
    float inv = 1.0f / s;
    e[tid]       = w0 * inv;
    e[tid + 256] = w1 * inv;
}

// ---------------- Kernel 3: out = gamma * (attn @ q) + x ----------------
// BM=64 (c) x BN=128 (n), BK=32 (d). A=attn row-major (K-contig frags, conflict-free).
// B=q gathered column-wise: each thread owns one n and an 8-wide d-block, 8 coalesced
// scalar loads -> one 16B ds_write at [n][ (dblk ^ sw(n))*16B ], sw(n)=(n^(n>>2))&3.
// Write and read both verified 8-dwords-per-bank even (conflict-free).
__global__ __launch_bounds__(256) void out_kernel(const float* __restrict__ x,
                                                  const float* __restrict__ attn,
                                                  const float* __restrict__ gamma,
                                                  float* __restrict__ out) {
    int blk = blockIdx.x;
    int b   = blk >> 8;                 // 256 tiles per batch (8 x 32)
    int t   = blk & 255;
    int c0  = (t >> 5) * 64;
    int n0  = (t & 31) * 128;
    const float* qb = x + (size_t)b * CCH * NSP;
    const float* ab = attn + (size_t)b * CCH * CCH;

    __shared__ short As[64][32];
    __shared__ short Bs[128][32];       // [n][d], 64B rows, XOR-swizzled 16B chunks
    char* bbase = (char*)&Bs[0][0];

    int tid  = threadIdx.x;
    int lane = tid & 63;
    int w    = tid >> 6;
    int wr   = (w >> 1) * 32;           // c offset of wave
    int wc   = (w & 1) * 64;            // n offset of wave

    int bn   = tid & 127;               // B-stage: this thread's n within tile
    int bsw  = (bn ^ (bn >> 2)) & 3;    // swizzle for that n
    int bdb0 = tid >> 7;                // 0..1 (d-block base)

    fx4 acc[2][4];
#pragma unroll
    for (int i = 0; i < 2; i++)
#pragma unroll
        for (int j = 0; j < 4; j++) acc[i][j] = (fx4)(0.0f);

    for (int kt = 0; kt < CCH / 32; ++kt) {
        __syncthreads();
        // A: 64x32 fp32 -> bf16 (truncation)
#pragma unroll
        for (int s = 0; s < 2; ++s) {
            int idx = s * 256 + tid;
            int r   = idx >> 3;
            int f4  = idx & 7;
            fx4 v = *(const fx4*)(ab + (size_t)(c0 + r) * CCH + kt * 32 + f4 * 4);
            bfx4 hv;
#pragma unroll
            for (int e = 0; e < 4; ++e) hv[e] = f2bf_trunc(v[e]);
            *(bfx4*)&As[r][f4 * 4] = hv;
        }
        // B: gather 8 d-values per n, pack, single 16B swizzled write
#pragma unroll
        for (int s = 0; s < 2; ++s) {
            int dblk = bdb0 + 2 * s;    // 0..3
            const float* p = qb + (size_t)(kt * 32 + dblk * 8) * NSP + n0 + bn;
            float v[8];
#pragma unroll
            for (int i = 0; i < 8; ++i) v[i] = p[(size_t)i * NSP];
            bfx8 pk;
#pragma unroll
            for (int i = 0; i < 8; ++i) pk[i] = f2bf_trunc(v[i]);
            *(bfx8*)(bbase + bn * 64 + ((dblk ^ bsw) << 4)) = pk;
        }
        __syncthreads();

        bfx8 af[2];
#pragma unroll
        for (int mi = 0; mi < 2; ++mi)
            af[mi] = *(const bfx8*)&As[wr + mi * 16 + (lane & 15)][(lane >> 4) * 8];
        bfx8 bf[4];
#pragma unroll
        for (int ni = 0; ni < 4; ++ni) {
            int n   = wc + ni * 16 + (lane & 15);
            int swn = (n ^ (n >> 2)) & 3;
            bf[ni] = *(const bfx8*)(bbase + n * 64 + (((lane >> 4) ^ swn) << 4));
        }
#pragma unroll
        for (int mi = 0; mi < 2; ++mi)
#pragma unroll
            for (int ni = 0; ni < 4; ++ni)
                acc[mi][ni] = __builtin_amdgcn_mfma_f32_16x16x32_bf16(af[mi], bf[ni], acc[mi][ni], 0, 0, 0);
    }

    float g = gamma[0];
    int colw = lane & 15;
    int rowg = (lane >> 4) * 4;
#pragma unroll
    for (int mi = 0; mi < 2; ++mi)
#pragma unroll
        for (int ni = 0; ni < 4; ++ni) {
            int n = n0 + wc + ni * 16 + colw;
#pragma unroll
            for (int r = 0; r < 4; ++r) {
                int c = c0 + wr + mi * 16 + rowg + r;
                size_t off = ((size_t)b * CCH + c) * NSP + n;
                out[off] = g * acc[mi][ni][r] + qb[(size_t)c * NSP + n];
            }
        }
}

extern "C" void kernel_launch(void* const* d_in, const int* in_sizes, int n_in,
                              void* d_out, int out_size, void* d_ws, size_t ws_size,
                              hipStream_t stream) {
    (void)in_sizes; (void)n_in; (void)out_size; (void)ws_size;
    const float* x     = (const float*)d_in[0];
    const float* gamma = (const float*)d_in[1];
    float*       out   = (float*)d_out;
    float*       energy = (float*)d_ws;   // B*C*C fp32 = 16 MiB

    energy_kernel <<<BATCH * 64, 256, 0, stream>>>(x, energy);
    softmax_kernel<<<BATCH * CCH, 256, 0, stream>>>(energy);
    out_kernel    <<<BATCH * 256, 256, 0, stream>>>(x, energy, gamma, out);
}